// Round 6
// baseline (1567.861 us; speedup 1.0000x reference)
//
#include <hip/hip_runtime.h>
#include <hip/hip_fp16.h>
#include <cstdio>

typedef unsigned short u16;
typedef __attribute__((ext_vector_type(8))) _Float16 f16x8;
typedef __attribute__((ext_vector_type(4))) float fv4;

#define TT 512
#define BB 256

__device__ __forceinline__ float us2f(u16 u) {
    union { u16 u; _Float16 h; } c; c.u = u; return (float)c.h;
}
__device__ __forceinline__ u16 f2us(float f) {
    union { u16 u; _Float16 h; } c; c.h = (_Float16)f; return c.u;
}

// async global->LDS, 16B per lane. LDS dest must be wave-uniform base + lane*16.
__device__ __forceinline__ void gl_lds16(const u16* g, u16* l) {
    __builtin_amdgcn_global_load_lds(
        (const __attribute__((address_space(1))) void*)g,
        (__attribute__((address_space(3))) void*)l, 16, 0, 0);
}

// CK-style LDS-only barrier: waits lgkmcnt(0)+expcnt(0) but leaves vmcnt
// untouched, so global loads/stores stay in flight across the barrier.
// imm encoding (gfx9/CDNA): vmcnt[3:0]@[3:0]=0xF, expcnt@[6:4]=0,
// lgkmcnt@[11:8]=0, vmcnt[5:4]@[15:14]=0x3  -> 0xC00F
__device__ __forceinline__ void sync_lds() {
    __builtin_amdgcn_s_waitcnt(0xC00F);
    __builtin_amdgcn_s_barrier();
}

// ---------------- fp32 -> fp16 convert (n % 8 == 0) ----------------
__global__ void cvt_f32_f16(const float* __restrict__ s, u16* __restrict__ d, int n) {
    long stride = (long)gridDim.x * blockDim.x * 8;
    for (long i = ((long)blockIdx.x * blockDim.x + threadIdx.x) * 8; i < n; i += stride) {
        f16x8 o;
#pragma unroll
        for (int j = 0; j < 8; ++j) o[j] = (_Float16)s[i + j];
        *(f16x8*)(d + i) = o;
    }
}

// ---------------- bias fold: bsum = b_ih + (j<512 ? b_hh : 0) ----------------
__global__ void bias_fold(const float* __restrict__ bih, const float* __restrict__ bhh,
                          float* __restrict__ bsum) {
    int i = blockIdx.x * blockDim.x + threadIdx.x;
    if (i < 768) bsum[i] = bih[i] + (i < 512 ? bhh[i] : 0.f);
}

// ---------------- pack W_hh [768,256] into MFMA B-frag order ----------------
// Wp[((jt*8 + kt)*64 + lane)*8 + i] = Whh[jt*16 + (lane&15)][kt*32 + (lane>>4)*8 + i]
__global__ void pack_whh(const float* __restrict__ W, u16* __restrict__ Wp) {
    int t = blockIdx.x * blockDim.x + threadIdx.x;   // 0..24575
    int l = t & 63;
    int kt = (t >> 6) & 7;
    int jt = t >> 9;                                  // 0..47
    int j = jt * 16 + (l & 15);
    int k = kt * 32 + (l >> 4) * 8;
    f16x8 o;
#pragma unroll
    for (int i = 0; i < 8; ++i) o[i] = (_Float16)W[j * 256 + k + i];
    *(f16x8*)(Wp + (size_t)t * 8) = o;
}

// ---------------- pack W2b [18,512] zero-padded to [32,512] in B-frag order --
__global__ void pack_w2b(const float* __restrict__ W, u16* __restrict__ Wp) {
    int t = blockIdx.x * blockDim.x + threadIdx.x;   // 0..2047
    int l = t & 63;
    int kt = (t >> 6) & 15;
    int nt = t >> 10;                                 // 0..1
    int n = nt * 16 + (l & 15);
    int k = kt * 32 + (l >> 4) * 8;
    f16x8 o;
#pragma unroll
    for (int i = 0; i < 8; ++i)
        o[i] = (n < 18) ? (_Float16)W[n * 512 + k + i] : (_Float16)0.f;
    *(f16x8*)(Wp + (size_t)t * 8) = o;
}

// ---------------- generic fp16 GEMM: C[m,n] = act(sum_k A[m,k]*B[n,k] + bias[n])
__global__ __launch_bounds__(256) void gemm_bt(
    const u16* __restrict__ A, const u16* __restrict__ B,
    const float* __restrict__ bias, u16* __restrict__ C,
    int N, int K, int act)
{
    __shared__ u16 Ash[4096] __attribute__((aligned(16)));
    __shared__ u16 Bsh[4096] __attribute__((aligned(16)));
    const int tid = threadIdx.x;
    const int l = tid & 63, w = tid >> 6;
    const long m0 = (long)blockIdx.y * 128;
    const int n0 = blockIdx.x * 128;
    const int r = tid >> 2, c8 = (tid & 3) * 8;
    const u16* gA0 = A + (m0 + r) * K + c8;
    const u16* gA1 = A + (m0 + 64 + r) * K + c8;
    const u16* gB0 = B + (long)(n0 + r) * K + c8;
    const u16* gB1 = B + (long)(n0 + 64 + r) * K + c8;
    const int mb = (w >> 1) * 64, nb = (w & 1) * 64;
    const int mrow = l & 15, colq = (l >> 4) * 8;
    fv4 acc[4][4] = {};
    for (int k0 = 0; k0 < K; k0 += 32) {
        gl_lds16(gA0 + k0, &Ash[tid * 8]);
        gl_lds16(gA1 + k0, &Ash[2048 + tid * 8]);
        gl_lds16(gB0 + k0, &Bsh[tid * 8]);
        gl_lds16(gB1 + k0, &Bsh[2048 + tid * 8]);
        __syncthreads();
        f16x8 af[4], bf[4];
#pragma unroll
        for (int i = 0; i < 4; ++i)
            af[i] = *(const f16x8*)&Ash[(mb + i * 16 + mrow) * 32 + colq];
#pragma unroll
        for (int i = 0; i < 4; ++i)
            bf[i] = *(const f16x8*)&Bsh[(nb + i * 16 + mrow) * 32 + colq];
#pragma unroll
        for (int mt = 0; mt < 4; ++mt)
#pragma unroll
            for (int nt = 0; nt < 4; ++nt)
                acc[mt][nt] = __builtin_amdgcn_mfma_f32_16x16x32_f16(
                    af[mt], bf[nt], acc[mt][nt], 0, 0, 0);
        __syncthreads();
    }
    float bv[4];
#pragma unroll
    for (int nt = 0; nt < 4; ++nt) bv[nt] = bias[n0 + nb + nt * 16 + mrow];
    const int rq = (l >> 4) * 4;
#pragma unroll
    for (int mt = 0; mt < 4; ++mt)
#pragma unroll
        for (int nt = 0; nt < 4; ++nt)
#pragma unroll
            for (int i = 0; i < 4; ++i) {
                float v = acc[mt][nt][i] + bv[nt];
                if (act) v = fmaxf(v, 0.f);
                C[(m0 + mb + mt * 16 + rq + i) * (long)N + (n0 + nb + nt * 16 + mrow)] = f2us(v);
            }
}

// ---------------- GI GEMM (N=768, K=256): stores into gru-packed layout -------
// GIp[((((t*16+blk)*8 + w)*64 + lane)*24 + u*4 + i] ; u = gate*2 + s
__global__ __launch_bounds__(256) void gemm_gi(
    const u16* __restrict__ A, const u16* __restrict__ B,
    const float* __restrict__ bias, u16* __restrict__ GIp)
{
    __shared__ u16 Ash[4096] __attribute__((aligned(16)));
    __shared__ u16 Bsh[4096] __attribute__((aligned(16)));
    const int tid = threadIdx.x;
    const int l = tid & 63, w = tid >> 6;
    const long m0 = (long)blockIdx.y * 128;
    const int n0 = blockIdx.x * 128;
    const int r = tid >> 2, c8 = (tid & 3) * 8;
    const u16* gA0 = A + (m0 + r) * 256 + c8;
    const u16* gA1 = A + (m0 + 64 + r) * 256 + c8;
    const u16* gB0 = B + (long)(n0 + r) * 256 + c8;
    const u16* gB1 = B + (long)(n0 + 64 + r) * 256 + c8;
    const int mb = (w >> 1) * 64, nb = (w & 1) * 64;
    const int mrow = l & 15, colq = (l >> 4) * 8;
    fv4 acc[4][4] = {};
    for (int k0 = 0; k0 < 256; k0 += 32) {
        gl_lds16(gA0 + k0, &Ash[tid * 8]);
        gl_lds16(gA1 + k0, &Ash[2048 + tid * 8]);
        gl_lds16(gB0 + k0, &Bsh[tid * 8]);
        gl_lds16(gB1 + k0, &Bsh[2048 + tid * 8]);
        __syncthreads();
        f16x8 af[4], bf[4];
#pragma unroll
        for (int i = 0; i < 4; ++i)
            af[i] = *(const f16x8*)&Ash[(mb + i * 16 + mrow) * 32 + colq];
#pragma unroll
        for (int i = 0; i < 4; ++i)
            bf[i] = *(const f16x8*)&Bsh[(nb + i * 16 + mrow) * 32 + colq];
#pragma unroll
        for (int mt = 0; mt < 4; ++mt)
#pragma unroll
            for (int nt = 0; nt < 4; ++nt)
                acc[mt][nt] = __builtin_amdgcn_mfma_f32_16x16x32_f16(
                    af[mt], bf[nt], acc[mt][nt], 0, 0, 0);
        __syncthreads();
    }
    float bv[4];
#pragma unroll
    for (int nt = 0; nt < 4; ++nt) bv[nt] = bias[n0 + nb + nt * 16 + mrow];
    const int rq = (l >> 4) * 4;
#pragma unroll
    for (int mt = 0; mt < 4; ++mt)
#pragma unroll
        for (int nt = 0; nt < 4; ++nt)
#pragma unroll
            for (int i = 0; i < 4; ++i) {
                float v = acc[mt][nt][i] + bv[nt];
                int m = (int)(m0 + mb + mt * 16 + rq + i);
                int n = n0 + nb + nt * 16 + mrow;
                int t  = m >> 8, b = m & 255;
                int blk = b >> 4, rb = b & 15, q = rb >> 2, i2 = rb & 3;
                int g = n >> 8, c = n & 255, w2 = c >> 5, s = (c >> 4) & 1, cl = c & 15;
                size_t idx = ((((size_t)t * 16 + blk) * 8 + w2) * 64 + (q * 16 + cl)) * 24
                             + (g * 2 + s) * 4 + i2;
                GIp[idx] = f2us(v);
            }
}

// ---------------- sequential GRU v5 --------------------------------------
// W_hh kt0-6 register-resident, enforced by TWO mechanisms (no inline asm):
//  1. Wp/Hout are plain (may-alias) pointers -> the in-loop Hout stores make
//     rematerializing the pre-loop W loads ILLEGAL (round-5 bug: invariant
//     loads got remat'd into the loop; VGPR_Count=128 proved it).
//  2. amdgpu_waves_per_eu(2,2) pins the occupancy target at 2 waves/SIMD ->
//     256-VGPR budget (wf=168 + acc 24 + misc ~50).
// kt7 in LDS (48KB) + single h buffer (8KB) = 56KB <= 64KB static cap.
// Barriers are lgkm-only (sync_lds) so Hout stores / gi loads stay in flight.
__global__ __launch_bounds__(512)
__attribute__((amdgpu_waves_per_eu(2, 2)))
void gru_seq5(u16* Wp, const u16* __restrict__ GIp,
              const float* __restrict__ bhh, u16* Hout)
{
    __shared__ u16 h_sh[4096] __attribute__((aligned(16)));   // h, A-frag layout
    __shared__ u16 Wl[24576] __attribute__((aligned(16)));    // kt7: [48][64][8]
    const int tid = threadIdx.x;
    const int l = tid & 63, w = tid >> 6;
    const int blk = blockIdx.x;
    const int bg = blk * 16;
    const int col = l & 15, quad = l >> 4;

    for (int i = tid; i < 4096; i += 512) h_sh[i] = 0;
    for (int idx = tid; idx < 3072; idx += 512)
        *(f16x8*)&Wl[(size_t)idx * 8] =
            *(const f16x8*)&Wp[(((size_t)(idx >> 6) * 8 + 7) * 64 + (idx & 63)) * 8];

    int jts[6];
#pragma unroll
    for (int g = 0; g < 3; ++g)
#pragma unroll
        for (int s = 0; s < 2; ++s) jts[g * 2 + s] = g * 16 + 2 * w + s;

    // W_hh fragments kt 0..6: 42 f16x8 = 168 VGPRs, must stay resident
    f16x8 wf[6][7];
#pragma unroll
    for (int u = 0; u < 6; ++u)
#pragma unroll
        for (int kt = 0; kt < 7; ++kt)
            wf[u][kt] = *(const f16x8*)&Wp[(((size_t)jts[u] * 8 + kt) * 64 + l) * 8];

    float hbn[2] = { bhh[512 + 32 * w + col], bhh[512 + 32 * w + 16 + col] };

    const u16* gbase = GIp + ((size_t)(blk * 8 + w) * 64 + l) * 24;
    float hold[2][4] = {};
    u16* hout_base = Hout + ((size_t)(bg + quad * 4) * 256) + 32 * w + col;
    __syncthreads();   // full drain once: Wl/h_sh staging complete

    for (int t = 0; t < TT; ++t) {
        // gi for this step: 3x16B loads, used only in the epilogue (~500cy later)
        const u16* gp = gbase + (size_t)t * 196608;
        f16x8 gcur[3];
#pragma unroll
        for (int j = 0; j < 3; ++j) gcur[j] = *(const f16x8*)(gp + j * 8);

        fv4 acc[6] = {};
#pragma unroll
        for (int kt = 0; kt < 7; ++kt) {
            f16x8 a = *(const f16x8*)&h_sh[(kt * 64 + l) * 8];
#pragma unroll
            for (int u = 0; u < 6; ++u)
                acc[u] = __builtin_amdgcn_mfma_f32_16x16x32_f16(a, wf[u][kt], acc[u], 0, 0, 0);
        }
        {
            f16x8 a = *(const f16x8*)&h_sh[(7 * 64 + l) * 8];
#pragma unroll
            for (int u = 0; u < 6; ++u) {
                f16x8 bw = *(const f16x8*)&Wl[(size_t)(jts[u] * 64 + l) * 8];
                acc[u] = __builtin_amdgcn_mfma_f32_16x16x32_f16(a, bw, acc[u], 0, 0, 0);
            }
        }
        sync_lds();   // all waves' h reads done (lgkm only; vmem stays in flight)

        u16* hp = hout_base + (size_t)t * 65536;
#pragma unroll
        for (int s = 0; s < 2; ++s) {
            const int q2 = s * 2 + (col >> 3);
#pragma unroll
            for (int i = 0; i < 4; ++i) {
                float pr  = (float)gcur[0][s * 4 + i] + acc[0 + s][i];   // biases folded
                float pz  = (float)gcur[1][s * 4 + i] + acc[2 + s][i];
                float h_n = acc[4 + s][i] + hbn[s];
                float rg = __builtin_amdgcn_rcpf(1.f + __expf(-pr));
                float zg = __builtin_amdgcn_rcpf(1.f + __expf(-pz));
                float pre = (float)gcur[2][s * 4 + i] + rg * h_n;
                float ea = __expf(-2.f * fabsf(pre));
                float th = (1.f - ea) * __builtin_amdgcn_rcpf(1.f + ea);
                float ng = (pre >= 0.f) ? th : -th;
                float hn = (1.f - zg) * ng + zg * hold[s][i];
                hold[s][i] = hn;
                u16 hu = f2us(hn);
                h_sh[(w * 64 + q2 * 16 + quad * 4 + i) * 8 + (col & 7)] = hu;
                hp[(size_t)i * 256 + s * 16] = hu;
            }
        }
        sync_lds();   // h writes visible before next step's reads
    }
}

// ---------------- head: out[m, 0..17] = Q1[m,:512] @ W2b^T + b2b (fp32 out) ---
__global__ __launch_bounds__(256) void head_gemm(
    const u16* __restrict__ Q1, const u16* __restrict__ W2p,
    const float* __restrict__ b2, float* __restrict__ out)
{
    __shared__ u16 Ash[4096] __attribute__((aligned(16)));
    __shared__ u16 Bsh[16384] __attribute__((aligned(16)));
    const int tid = threadIdx.x;
    const int l = tid & 63, w = tid >> 6;
    const long m0 = (long)blockIdx.x * 128;
    const int col = l & 15, quad = l >> 4, colq = quad * 8;
    for (int i = tid * 8; i < 16384; i += 2048)
        *(f16x8*)&Bsh[i] = *(const f16x8*)&W2p[i];
    const int r = tid >> 2, c8 = (tid & 3) * 8;
    const u16* gA0 = Q1 + (m0 + r) * 512 + c8;
    const u16* gA1 = Q1 + (m0 + 64 + r) * 512 + c8;
    fv4 acc[2][2] = {};
    for (int k0 = 0; k0 < 512; k0 += 32) {
        gl_lds16(gA0 + k0, &Ash[tid * 8]);
        gl_lds16(gA1 + k0, &Ash[2048 + tid * 8]);
        __syncthreads();
        const int kt = k0 >> 5;
        f16x8 af[2], bf[2];
#pragma unroll
        for (int mt = 0; mt < 2; ++mt)
            af[mt] = *(const f16x8*)&Ash[(w * 32 + mt * 16 + col) * 32 + colq];
#pragma unroll
        for (int nt = 0; nt < 2; ++nt)
            bf[nt] = *(const f16x8*)&Bsh[((nt * 16 + kt) * 64 + l) * 8];
#pragma unroll
        for (int mt = 0; mt < 2; ++mt)
#pragma unroll
            for (int nt = 0; nt < 2; ++nt)
                acc[mt][nt] = __builtin_amdgcn_mfma_f32_16x16x32_f16(
                    af[mt], bf[nt], acc[mt][nt], 0, 0, 0);
        __syncthreads();
    }
    const int rq = quad * 4;
#pragma unroll
    for (int nt = 0; nt < 2; ++nt) {
        int c = nt * 16 + col;
        if (c < 18) {
            float bias = b2[c];
#pragma unroll
            for (int mt = 0; mt < 2; ++mt)
#pragma unroll
                for (int i = 0; i < 4; ++i)
                    out[(m0 + w * 32 + mt * 16 + rq + i) * 18 + c] = acc[mt][nt][i] + bias;
        }
    }
}

extern "C" void kernel_launch(void* const* d_in, const int* in_sizes, int n_in,
                              void* d_out, int out_size, void* d_ws, size_t ws_size,
                              hipStream_t stream) {
    const float* x   = (const float*)d_in[0];
    const float* W1a = (const float*)d_in[1];
    const float* b1a = (const float*)d_in[2];
    const float* W1b = (const float*)d_in[3];
    const float* b1b = (const float*)d_in[4];
    const float* Wih = (const float*)d_in[5];
    const float* bih = (const float*)d_in[6];
    const float* Whh = (const float*)d_in[7];
    const float* bhh = (const float*)d_in[8];
    const float* W2a = (const float*)d_in[9];
    const float* b2a = (const float*)d_in[10];
    const float* W2b = (const float*)d_in[11];
    const float* b2b = (const float*)d_in[12];

    char* ws = (char*)d_ws;
    u16* R    = (u16*)ws;                 // A1 [131072,512]f16, then GIp packed
    u16* A2b  = (u16*)(ws + 201326592);   // 67108864 B
    u16* XH   = (u16*)(ws + 268435456);   // 67108864 B (x fp16, later Hout)
    float* bsum = (float*)(ws + 268435456 + 67108864 - 4096);
    u16* W1ah = (u16*)(ws + 335544320);   //   262144 B
    u16* W1bh = (u16*)(ws + 335806464);   //   262144 B
    u16* Wihh = (u16*)(ws + 336068608);   //   393216 B
    u16* W2ah = (u16*)(ws + 336461824);   //   262144 B
    u16* Wpk  = (u16*)(ws + 336723968);   //   393216 B
    u16* W2p  = (u16*)(ws + 337117184);   //    32768 B
    if (ws_size < 337149952) {
        fprintf(stderr, "kernel_launch: ws too small (%zu < 337149952)\n", ws_size);
    }

    cvt_f32_f16<<<dim3(2048), dim3(256), 0, stream>>>(x, XH, 33554432);
    cvt_f32_f16<<<dim3(64), dim3(256), 0, stream>>>(W1a, W1ah, 131072);
    cvt_f32_f16<<<dim3(64), dim3(256), 0, stream>>>(W1b, W1bh, 131072);
    cvt_f32_f16<<<dim3(96), dim3(256), 0, stream>>>(Wih, Wihh, 196608);
    cvt_f32_f16<<<dim3(64), dim3(256), 0, stream>>>(W2a, W2ah, 131072);
    pack_whh<<<dim3(96), dim3(256), 0, stream>>>(Whh, Wpk);
    pack_w2b<<<dim3(8), dim3(256), 0, stream>>>(W2b, W2p);

    // Phase A
    gemm_bt<<<dim3(4, 1024), dim3(256), 0, stream>>>(XH, W1ah, b1a, R,   512, 256, 1);
    bias_fold<<<dim3(3), dim3(256), 0, stream>>>(bih, bhh, bsum);
    gemm_bt<<<dim3(2, 1024), dim3(256), 0, stream>>>(R,  W1bh, b1b, A2b, 256, 512, 1);
    gemm_gi<<<dim3(6, 1024), dim3(256), 0, stream>>>(A2b, Wihh, bsum, R);
    // Phase R: sequential GRU
    gru_seq5<<<dim3(16), dim3(512), 0, stream>>>(Wpk, R, bhh, XH);
    // Phase B
    gemm_bt<<<dim3(4, 1024), dim3(256), 0, stream>>>(XH, W2ah, b2a, R, 512, 256, 1);
    head_gemm<<<dim3(1024), dim3(256), 0, stream>>>(R, W2p, b2b, (float*)d_out);
}